// Round 14
// baseline (732.073 us; speedup 1.0000x reference)
//
#include <hip/hip_runtime.h>
#include <hip/hip_bf16.h>

#define NN 50000
#define NE 800000
#define NG 512
#define HD 128
#define ED 64
#define GD 64
#define HID 128
#define EB 128  // edges per block in edge_kernel (8 waves x 16)

typedef __attribute__((ext_vector_type(8))) short short8;
typedef __attribute__((ext_vector_type(4))) short short4v;
typedef __attribute__((ext_vector_type(2))) float f32x2;
typedef __attribute__((ext_vector_type(4))) float f32x4;

__device__ __forceinline__ short f2bf(float f) {
  union { float f; unsigned u; } v; v.f = f;
  unsigned r = v.u + 0x7fffu + ((v.u >> 16) & 1u);
  return (short)(r >> 16);
}

__device__ __forceinline__ float bf2f(short s) {
  union { unsigned u; float f; } v;
  v.u = ((unsigned)(unsigned short)s) << 16;
  return v.f;
}

__device__ __forceinline__ short8 load_a8(const float* p) {
  const f32x4* q = (const f32x4*)p;
  f32x4 x0 = q[0], x1 = q[1];
  short8 r;
  r[0]=f2bf(x0[0]); r[1]=f2bf(x0[1]); r[2]=f2bf(x0[2]); r[3]=f2bf(x0[3]);
  r[4]=f2bf(x1[0]); r[5]=f2bf(x1[1]); r[6]=f2bf(x1[2]); r[7]=f2bf(x1[3]);
  return r;
}

// swizzled LDS index (in shorts). rowBytes = row stride in bytes.
__device__ __forceinline__ int swz(int row, int col, int rowBytes) {
  int b = row * rowBytes + col * 2;
  b ^= (row & 7) << 4;
  return b >> 1;
}

// Cast h, g to bf16 + degree count + weight pack, all fused (one launch).
__global__ void cast_kernel(const float* __restrict__ h, const float* __restrict__ g,
                            const int* __restrict__ ei,
                            const float* __restrict__ Wm1, const float* __restrict__ Wm2,
                            const float* __restrict__ We1, const float* __restrict__ We2,
                            const float* __restrict__ Wh1, const float* __restrict__ Wh2,
                            short* __restrict__ h_bf, short* __restrict__ g_bf,
                            int* __restrict__ deg, short* __restrict__ pout) {
  int gid = blockIdx.x * 256 + threadIdx.x;
  const int H4 = NN * HD / 4;          // 1,600,000
  const int G4 = NG * GD / 4;          // 8,192
  if (gid < H4) {
    f32x4 v = ((const f32x4*)h)[gid];
    short4v r; r[0]=f2bf(v[0]); r[1]=f2bf(v[1]); r[2]=f2bf(v[2]); r[3]=f2bf(v[3]);
    *(short4v*)(h_bf + gid * 4) = r;
  } else if (gid < H4 + G4) {
    int i = gid - H4;
    f32x4 v = ((const f32x4*)g)[i];
    short4v r; r[0]=f2bf(v[0]); r[1]=f2bf(v[1]); r[2]=f2bf(v[2]); r[3]=f2bf(v[3]);
    *(short4v*)(g_bf + i * 4) = r;
  } else if (gid < H4 + G4 + NE) {
    int i = gid - H4 - G4;
    atomicAdd(&deg[ei[NE + i]], 1);
  } else if (gid < H4 + G4 + NE + 135168) {
    int pid = gid - H4 - G4 - NE;
    const float* W; int Ncol, base, idx;
    if (pid < 49152)       { W = Wm1; Ncol = 128; base = 0;      idx = pid; }
    else if (pid < 65536)  { W = Wm2; Ncol = 128; base = 49152;  idx = pid - 49152; }
    else if (pid < 73728)  { W = We1; Ncol = 64;  base = 65536;  idx = pid - 65536; }
    else if (pid < 77824)  { W = We2; Ncol = 64;  base = 73728;  idx = pid - 73728; }
    else if (pid < 118784) { W = Wh1; Ncol = 128; base = 77824;  idx = pid - 77824; }
    else                   { W = Wh2; Ncol = 128; base = 118784; idx = pid - 118784; }
    int k = idx / Ncol, n = idx % Ncol;
    pout[base + (k >> 3) * Ncol * 8 + n * 8 + (k & 7)] = f2bf(W[idx]);
  }
}

__global__ __launch_bounds__(1024) void scan_kernel(int* __restrict__ deg) {
  __shared__ int psum[1024];
  const int CH = 49;
  int t = threadIdx.x;
  int lo = t * CH, hi = lo + CH; if (hi > NN) hi = NN; if (lo > NN) lo = NN;
  int s = 0;
  for (int i = lo; i < hi; ++i) s += deg[i];
  psum[t] = s;
  __syncthreads();
  for (int d = 1; d < 1024; d <<= 1) {
    int v = (t >= d) ? psum[t - d] : 0;
    __syncthreads();
    psum[t] += v;
    __syncthreads();
  }
  int run = (t == 0) ? 0 : psum[t - 1];
  for (int i = lo; i < hi; ++i) { int v = deg[i]; deg[i] = run; run += v; }
}

__global__ void scatter_kernel(const int* __restrict__ ei, int* __restrict__ off,
                               int* __restrict__ elist) {
  int i = blockIdx.x * 256 + threadIdx.x;
  if (i < NE) {
    int d = ei[NE + i];
    int p = atomicAdd(&off[d], 1);
    elist[p] = i;
  }
}

// Edge kernel v12: EB=128, 8 waves x 16 edges, 512 threads. Staging traffic
// and barrier count per edge halved vs v11; We1/We2 staged too (pre-staged
// before the flush so e2 needs no extra barrier). LDS 50.7KB -> 3 blocks/CU
// x 8 waves = 24 waves/CU (~75% occ at VGPR 64).
__global__ __launch_bounds__(512) void edge_kernel(
    const short* __restrict__ h_bf, const int* __restrict__ ei,
    const float* __restrict__ e, const short* __restrict__ g_bf,
    const int* __restrict__ batch, const int* __restrict__ elist,
    const short* __restrict__ pWm1, const float* __restrict__ bm1,
    const short* __restrict__ pWm2, const float* __restrict__ bm2,
    const float* __restrict__ Wma, const float* __restrict__ bma,
    const short* __restrict__ pWe1, const float* __restrict__ be1,
    const short* __restrict__ pWe2, const float* __restrict__ be2,
    float* __restrict__ e_out, float* __restrict__ m_aggr) {
  __shared__ short lds_m[EB * 128];   // 32 KB
  __shared__ short bufB[2][4096];     // 16 KB
  __shared__ float att_s[EB];
  __shared__ int sdst[EB];
  __shared__ int seid[EB];
  short* ebuf = lds_m;                // reused after flush: 128 x 64 bf16

  const int tid = threadIdx.x;        // 0..511
  const int w = tid >> 6;             // 0..7
  const int lane = tid & 63;
  const int row16 = lane & 15;
  const int quad = lane >> 4;

  // one 8KB chunk: 512 threads x 16B, coalesced
#define STAGE(Wp, c, b) \
    *(short8*)&bufB[(b)][tid * 8] = *(const short8*)((Wp) + (size_t)(c) * 4096 + tid * 8)

  // bijective XCD-chunked swizzle (m204); nwg = 6250
  int nwg = gridDim.x;
  int q = nwg >> 3, rr = nwg & 7;
  int xcd = blockIdx.x & 7;
  int idx = blockIdx.x >> 3;
  int bid = (xcd < rr ? xcd * (q + 1) : rr * (q + 1) + (xcd - rr) * q) + idx;
  const int eb = bid * EB;

  if (tid < EB) {
    int eid = elist[eb + tid];
    seid[tid] = eid;
    sdst[tid] = ei[NE + eid];
  }

  const int eidr = elist[eb + w * 16 + row16];
  const int dstr = ei[NE + eidr];
  const int srcr = ei[eidr];
  const int gbr = batch[dstr];

  const short* seg0 = h_bf + (size_t)srcr * HD;
  const short* seg1 = h_bf + (size_t)dstr * HD;
  const short* seg3 = g_bf + (size_t)gbr * GD;

  // hoist e row once: f32 -> bf16 regs
  short8 ea0, ea1;
  {
    const float* ep = e + (size_t)eidr * ED + quad * 8;
    ea0 = load_a8(ep);
    ea1 = load_a8(ep + 32);
  }

  // ---- layer m1: [16,384] @ [384,128]; 12 staged k-chunks
  f32x4 acc[8];
#pragma unroll
  for (int t = 0; t < 8; ++t) acc[t] = (f32x4)0.0f;

  STAGE(pWm1, 0, 0);
  __syncthreads();
#pragma unroll
  for (int c = 0; c < 12; ++c) {
    if (c < 11) STAGE(pWm1, c + 1, (c + 1) & 1);
    else        STAGE(pWm2, 0, 0);   // (c+1)&1 == 0
    short8 a;
    if (c < 4)       a = *(const short8*)(seg0 + c * 32 + quad * 8);
    else if (c < 8)  a = *(const short8*)(seg1 + (c - 4) * 32 + quad * 8);
    else if (c == 8) a = ea0;
    else if (c == 9) a = ea1;
    else             a = *(const short8*)(seg3 + (c - 10) * 32 + quad * 8);
    const short* bc = &bufB[c & 1][quad * 1024 + row16 * 8];
#pragma unroll
    for (int t = 0; t < 8; ++t) {
      short8 b = *(const short8*)(bc + t * 128);
      acc[t] = __builtin_amdgcn_mfma_f32_16x16x32_bf16(a, b, acc[t], 0, 0, 0);
    }
    __syncthreads();
  }
#pragma unroll
  for (int t = 0; t < 8; ++t) {
    float b1 = bm1[t * 16 + row16];
#pragma unroll
    for (int r = 0; r < 4; ++r) {
      float y = fmaxf(acc[t][r] + b1, 0.f);
      lds_m[swz(w * 16 + quad * 4 + r, t * 16 + row16, 256)] = f2bf(y);
    }
  }

  // ---- layer m2: [16,128] @ [128,128]; 4 staged k-chunks; last iter
  // prefetches We1 chunk 0 into buf0.
  f32x4 acc2[8];
#pragma unroll
  for (int t = 0; t < 8; ++t) acc2[t] = (f32x4)0.0f;
#pragma unroll
  for (int c = 0; c < 4; ++c) {
    if (c < 3) STAGE(pWm2, c + 1, (c + 1) & 1);
    else       STAGE(pWe1, 0, 0);    // (c+1)&1 == 0
    short8 a = *(const short8*)&lds_m[swz(w * 16 + row16, c * 32 + quad * 8, 256)];
    const short* bc = &bufB[c & 1][quad * 1024 + row16 * 8];
#pragma unroll
    for (int t = 0; t < 8; ++t) {
      short8 b = *(const short8*)(bc + t * 128);
      acc2[t] = __builtin_amdgcn_mfma_f32_16x16x32_bf16(a, b, acc2[t], 0, 0, 0);
    }
    __syncthreads();
  }

  // m = relu(acc2+b) -> lds_m (raw m; att applied at flush); att partials
  float p[4] = {0.f, 0.f, 0.f, 0.f};
#pragma unroll
  for (int t = 0; t < 8; ++t) {
    float b2 = bm2[t * 16 + row16];
    float wv = Wma[t * 16 + row16];
#pragma unroll
    for (int r = 0; r < 4; ++r) {
      float y = fmaxf(acc2[t][r] + b2, 0.f);
      lds_m[swz(w * 16 + quad * 4 + r, t * 16 + row16, 256)] = f2bf(y);
      p[r] += y * wv;
    }
  }

#pragma unroll
  for (int s = 1; s < 16; s <<= 1) {
#pragma unroll
    for (int r = 0; r < 4; ++r) p[r] += __shfl_xor(p[r], s, 64);
  }
  {
    float bma0 = bma[0];
    if (row16 == 0) {
#pragma unroll
      for (int r = 0; r < 4; ++r)
        att_s[w * 16 + quad * 4 + r] = 1.f / (1.f + __expf(-(p[r] + bma0)));
    }
  }

  // ---- layer e1: [16,128] @ [128,64]; B staged (2 chunks of 2 c-iters).
  // buf0 = We1 chunk0 (c=0,1); buf1 = We1 chunk1 (c=2,3); We2 -> buf0 during
  // c=2 (after the c=1->c=2 barrier, so no read-write race on buf0).
  f32x4 acc3[4];
#pragma unroll
  for (int t = 0; t < 4; ++t) acc3[t] = (f32x4)0.0f;
#pragma unroll
  for (int c = 0; c < 4; ++c) {
    if (c == 0) STAGE(pWe1, 1, 1);
    if (c == 2) STAGE(pWe2, 0, 0);
    short8 a = *(const short8*)&lds_m[swz(w * 16 + row16, c * 32 + quad * 8, 256)];
    const short* bc = &bufB[(c >> 1) & 1][((c & 1) * 4 + quad) * 512 + row16 * 8];
#pragma unroll
    for (int t = 0; t < 4; ++t) {
      short8 b = *(const short8*)(bc + t * 128);
      acc3[t] = __builtin_amdgcn_mfma_f32_16x16x32_bf16(a, b, acc3[t], 0, 0, 0);
    }
    if (c == 1 || c == 3) __syncthreads();
  }

  // ---- segmented flush: 64 col-pairs x 8 row-quarters of 16 (quarter == wave)
  {
    int cp = tid & 63;
    int r0 = (tid >> 6) * 16;
    int cur = sdst[r0];
    float s0 = 0.f, s1 = 0.f;
    bool first = true;
#pragma unroll 1
    for (int r = r0; r < r0 + 16; ++r) {
      int d = sdst[r];
      unsigned u = *(const unsigned*)&lds_m[swz(r, cp * 2, 256)];
      float av = att_s[r];
      float v0 = bf2f((short)(u & 0xffffu)) * av;
      float v1 = bf2f((short)(u >> 16)) * av;
      if (d != cur) {
        if (first) {
          atomicAdd(&m_aggr[(size_t)cur * HID + cp * 2], s0);
          atomicAdd(&m_aggr[(size_t)cur * HID + cp * 2 + 1], s1);
        } else {
          f32x2 st; st[0] = s0; st[1] = s1;
          *(f32x2*)&m_aggr[(size_t)cur * HID + cp * 2] = st;
        }
        first = false; cur = d; s0 = v0; s1 = v1;
      } else {
        s0 += v0; s1 += v1;
      }
    }
    atomicAdd(&m_aggr[(size_t)cur * HID + cp * 2], s0);
    atomicAdd(&m_aggr[(size_t)cur * HID + cp * 2 + 1], s1);
  }

  __syncthreads();

  // ---- e1 bias+relu -> ebuf (overlays lds_m)
#pragma unroll
  for (int t = 0; t < 4; ++t) {
    float b1 = be1[t * 16 + row16];
#pragma unroll
    for (int r = 0; r < 4; ++r) {
      float y = fmaxf(acc3[t][r] + b1, 0.f);
      ebuf[swz(w * 16 + quad * 4 + r, t * 16 + row16, 128)] = f2bf(y);
    }
  }

  // ---- layer e2: [16,64] @ [64,64]; B pre-staged in buf0 (no barrier needed:
  // buf0 untouched since the c=3 barrier)
  f32x4 acc4[4];
#pragma unroll
  for (int t = 0; t < 4; ++t) acc4[t] = (f32x4)0.0f;
#pragma unroll
  for (int c = 0; c < 2; ++c) {
    short8 a = *(const short8*)&ebuf[swz(w * 16 + row16, c * 32 + quad * 8, 128)];
    const short* bc = &bufB[0][(c * 4 + quad) * 512 + row16 * 8];
#pragma unroll
    for (int t = 0; t < 4; ++t) {
      short8 b = *(const short8*)(bc + t * 128);
      acc4[t] = __builtin_amdgcn_mfma_f32_16x16x32_bf16(a, b, acc4[t], 0, 0, 0);
    }
  }

  // ---- e_out = relu(e + upd); residual from e f32 (L2-hot)
  int eidS[4];
#pragma unroll
  for (int r = 0; r < 4; ++r) eidS[r] = seid[w * 16 + quad * 4 + r];
#pragma unroll
  for (int t = 0; t < 4; ++t) {
    float b2 = be2[t * 16 + row16];
#pragma unroll
    for (int r = 0; r < 4; ++r) {
      int col = t * 16 + row16;
      float res = e[(size_t)eidS[r] * ED + col];
      float v = res + acc4[t][r] + b2;
      e_out[(size_t)eidS[r] * ED + col] = fmaxf(v, 0.f);
    }
  }
#undef STAGE
}

// stage one 8KB chunk with 256 threads: 2 x 16B each
#define STAGE_N(Wp, c, b) do {                                                \
    const short* _s = (Wp) + (size_t)(c) * 4096;                              \
    short8 _v0 = *(const short8*)(_s + tid * 8);                              \
    short8 _v1 = *(const short8*)(_s + 2048 + tid * 8);                       \
    *(short8*)&bufB[(b)][tid * 8] = _v0;                                      \
    *(short8*)&bufB[(b)][2048 + tid * 8] = _v1;                               \
  } while (0)

// Node kernel (R13, staged — neutral but kept): 64 nodes/block, 4 waves.
__global__ __launch_bounds__(256) void node_kernel(
    const float* __restrict__ h, const short* __restrict__ h_bf,
    const float* __restrict__ m_aggr, const short* __restrict__ g_bf,
    const int* __restrict__ batch,
    const short* __restrict__ pWh1, const float* __restrict__ bh1,
    const short* __restrict__ pWh2, const float* __restrict__ bh2,
    const float* __restrict__ Wha, const float* __restrict__ bha,
    float* __restrict__ h_out, float* __restrict__ h_aggr) {
  __shared__ short lds_y[64 * 128];   // 16 KB
  __shared__ short bufB[2][4096];     // 16 KB
  __shared__ int sbat[64];

  const int tid = threadIdx.x;
  const int w = tid >> 6;
  const int lane = tid & 63;
  const int row16 = lane & 15;
  const int quad = lane >> 4;
  const int nbase = blockIdx.x * 64;

  int nA = nbase + w * 16 + row16;
  int nAc = nA < NN ? nA : NN - 1;
  int gbA = batch[nAc];
  if (tid < 64) {
    int nn = nbase + tid;
    sbat[tid] = (nn < NN) ? batch[nn] : -1;
  }

  const short* seg0 = h_bf + (size_t)nAc * HD;
  const short* seg3 = g_bf + (size_t)gbA * GD;

  short8 ma[4];
  {
    const float* mp = m_aggr + (size_t)nAc * HID + quad * 8;
#pragma unroll
    for (int c = 0; c < 4; ++c) ma[c] = load_a8(mp + c * 32);
  }

  f32x4 acc[8];
#pragma unroll
  for (int t = 0; t < 8; ++t) acc[t] = (f32x4)0.0f;

  STAGE_N(pWh1, 0, 0);
  __syncthreads();
#pragma unroll
  for (int c = 0; c < 10; ++c) {
    if (c < 9) STAGE_N(pWh1, c + 1, (c + 1) & 1);
    else       STAGE_N(pWh2, 0, 0);
    short8 a;
    if (c < 4)      a = *(const short8*)(seg0 + c * 32 + quad * 8);
    else if (c < 8) a = ma[c - 4];
    else            a = *(const short8*)(seg3 + (c - 8) * 32 + quad * 8);
    const short* bc = &bufB[c & 1][quad * 1024 + row16 * 8];
#pragma unroll
    for (int t = 0; t < 8; ++t) {
      short8 b = *(const short8*)(bc + t * 128);
      acc[t] = __builtin_amdgcn_mfma_f32_16x16x32_bf16(a, b, acc[t], 0, 0, 0);
    }
    __syncthreads();
  }
#pragma unroll
  for (int t = 0; t < 8; ++t) {
    float b1 = bh1[t * 16 + row16];
#pragma unroll
    for (int r = 0; r < 4; ++r) {
      float y = fmaxf(acc[t][r] + b1, 0.f);
      lds_y[swz(w * 16 + quad * 4 + r, t * 16 + row16, 256)] = f2bf(y);
    }
  }

  f32x4 acc2[8];
#pragma unroll
  for (int t = 0; t < 8; ++t) acc2[t] = (f32x4)0.0f;
#pragma unroll
  for (int c = 0; c < 4; ++c) {
    if (c < 3) STAGE_N(pWh2, c + 1, (c + 1) & 1);
    short8 a = *(const short8*)&lds_y[swz(w * 16 + row16, c * 32 + quad * 8, 256)];
    const short* bc = &bufB[c & 1][quad * 1024 + row16 * 8];
#pragma unroll
    for (int t = 0; t < 8; ++t) {
      short8 b = *(const short8*)(bc + t * 128);
      acc2[t] = __builtin_amdgcn_mfma_f32_16x16x32_bf16(a, b, acc2[t], 0, 0, 0);
    }
    __syncthreads();
  }

  float hval[8][4];
  int nS[4];
#pragma unroll
  for (int r = 0; r < 4; ++r) nS[r] = nbase + w * 16 + quad * 4 + r;
#pragma unroll
  for (int t = 0; t < 8; ++t) {
    float b2 = bh2[t * 16 + row16];
#pragma unroll
    for (int r = 0; r < 4; ++r) {
      float v = 0.f;
      if (nS[r] < NN) {
        v = h[(size_t)nS[r] * HD + t * 16 + row16] + acc2[t][r] + b2;
        v = fmaxf(v, 0.f);
        h_out[(size_t)nS[r] * HD + t * 16 + row16] = v;
      }
      hval[t][r] = v;
    }
  }

  float part[4] = {0.f, 0.f, 0.f, 0.f};
#pragma unroll
  for (int t = 0; t < 8; ++t) {
    float wv = Wha[t * 16 + row16];
#pragma unroll
    for (int r = 0; r < 4; ++r) part[r] += hval[t][r] * wv;
  }
#pragma unroll
  for (int s = 1; s < 16; s <<= 1) {
#pragma unroll
    for (int r = 0; r < 4; ++r) part[r] += __shfl_xor(part[r], s, 64);
  }
  float bha0 = bha[0];
#pragma unroll
  for (int t = 0; t < 8; ++t)
#pragma unroll
    for (int r = 0; r < 4; ++r)
      lds_y[swz(w * 16 + quad * 4 + r, t * 16 + row16, 256)] =
          f2bf((part[r] + bha0) * hval[t][r]);

  __syncthreads();

  {
    int col = tid & 127;
    int r0 = (tid >> 7) * 32;
    int cur = sbat[r0];
    float sum = 0.f;
    bool first = true;
#pragma unroll 1
    for (int r = r0; r < r0 + 32; ++r) {
      int d = sbat[r];
      float v = bf2f(lds_y[swz(r, col, 256)]);
      if (d != cur) {
        if (cur >= 0) {
          if (first) atomicAdd(&h_aggr[(size_t)cur * HD + col], sum);
          else h_aggr[(size_t)cur * HD + col] = sum;
        }
        first = false; cur = d; sum = v;
      } else {
        sum += v;
      }
    }
    if (cur >= 0) atomicAdd(&h_aggr[(size_t)cur * HD + col], sum);
  }
}

// Global kernel: one wave per graph row
__global__ void g_kernel(const float* __restrict__ g, const float* __restrict__ h_aggr,
                         const float* __restrict__ Wg1, const float* __restrict__ bg1,
                         const float* __restrict__ Wg2, const float* __restrict__ bg2,
                         float* __restrict__ g_out) {
  __shared__ float cat[192];
  __shared__ float y1[64];
  int r = blockIdx.x;
  int t = threadIdx.x;  // 64 threads
  cat[t] = g[(size_t)r * GD + t];
  cat[64 + t] = h_aggr[(size_t)r * HD + t];
  cat[128 + t] = h_aggr[(size_t)r * HD + 64 + t];
  __syncthreads();
  float a = bg1[t];
  for (int k = 0; k < 192; ++k) a += cat[k] * Wg1[k * 64 + t];
  y1[t] = fmaxf(a, 0.f);
  __syncthreads();
  float b = bg2[t];
  for (int k = 0; k < 64; ++k) b += y1[k] * Wg2[k * 64 + t];
  float v = g[(size_t)r * GD + t] + b;
  g_out[(size_t)r * GD + t] = fmaxf(v, 0.f);
}

extern "C" void kernel_launch(void* const* d_in, const int* in_sizes, int n_in,
                              void* d_out, int out_size, void* d_ws, size_t ws_size,
                              hipStream_t stream) {
  const float* h = (const float*)d_in[0];
  const int* ei = (const int*)d_in[1];
  const float* e = (const float*)d_in[2];
  const float* g = (const float*)d_in[3];
  const int* batch = (const int*)d_in[4];
  const float* Wm1 = (const float*)d_in[5];
  const float* bm1 = (const float*)d_in[6];
  const float* Wm2 = (const float*)d_in[7];
  const float* bm2 = (const float*)d_in[8];
  const float* Wma = (const float*)d_in[9];
  const float* bma = (const float*)d_in[10];
  const float* We1 = (const float*)d_in[11];
  const float* be1 = (const float*)d_in[12];
  const float* We2 = (const float*)d_in[13];
  const float* be2 = (const float*)d_in[14];
  const float* Wh1 = (const float*)d_in[15];
  const float* bh1 = (const float*)d_in[16];
  const float* Wh2 = (const float*)d_in[17];
  const float* bh2 = (const float*)d_in[18];
  const float* Wha = (const float*)d_in[19];
  const float* bha = (const float*)d_in[20];
  const float* Wg1 = (const float*)d_in[21];
  const float* bg1 = (const float*)d_in[22];
  const float* Wg2 = (const float*)d_in[23];
  const float* bg2 = (const float*)d_in[24];

  float* out = (float*)d_out;
  float* h_out = out;
  float* e_out = out + (size_t)NN * HD;
  float* g_out = e_out + (size_t)NE * ED;

  char* ws = (char*)d_ws;
  float* m_aggr = (float*)ws;                     // 25,600,000 B
  float* h_aggr = (float*)(ws + 25600000);        // 262,144 B
  short* packed = (short*)(ws + 25862144);        // 270,336 B
  int* deg      = (int*)(ws + 26132480);          // 200,000 B
  int* elist    = (int*)(ws + 26332480);          // 3,200,000 B
  short* h_bf   = (short*)(ws + 29532480);        // 12,800,000 B
  short* g_bf   = (short*)(ws + 42332480);        // 65,536 B
  short* pWm1 = packed;
  short* pWm2 = packed + 49152;
  short* pWe1 = packed + 65536;
  short* pWe2 = packed + 73728;
  short* pWh1 = packed + 77824;
  short* pWh2 = packed + 118784;

  hipMemsetAsync(m_aggr, 0, (size_t)NN * HID * 4, stream);
  hipMemsetAsync(h_aggr, 0, (size_t)NG * HD * 4, stream);
  hipMemsetAsync(deg, 0, (size_t)NN * 4, stream);

  // grid: H4 + G4 + NE + pack(135168) = 2,543,360 threads
  cast_kernel<<<(2543360 + 255) / 256, 256, 0, stream>>>(
      h, g, ei, Wm1, Wm2, We1, We2, Wh1, Wh2, h_bf, g_bf, deg, packed);
  scan_kernel<<<1, 1024, 0, stream>>>(deg);
  scatter_kernel<<<(NE + 255) / 256, 256, 0, stream>>>(ei, deg, elist);

  edge_kernel<<<NE / EB, 512, 0, stream>>>(h_bf, ei, e, g_bf, batch, elist,
                                           pWm1, bm1, pWm2, bm2, Wma, bma,
                                           pWe1, be1, pWe2, be2, e_out, m_aggr);

  node_kernel<<<(NN + 63) / 64, 256, 0, stream>>>(h, h_bf, m_aggr, g_bf, batch,
                                                  pWh1, bh1, pWh2, bh2, Wha, bha,
                                                  h_out, h_aggr);

  g_kernel<<<NG, 64, 0, stream>>>(g, h_aggr, Wg1, bg1, Wg2, bg2, g_out);
}

// Round 15
// 607.964 us; speedup vs baseline: 1.2041x; 1.2041x over previous
//
#include <hip/hip_runtime.h>
#include <hip/hip_bf16.h>

#define NN 50000
#define NE 800000
#define NG 512
#define HD 128
#define ED 64
#define GD 64
#define HID 128
#define EB 64  // edges per block in edge_kernel

typedef __attribute__((ext_vector_type(8))) short short8;
typedef __attribute__((ext_vector_type(4))) short short4v;
typedef __attribute__((ext_vector_type(2))) float f32x2;
typedef __attribute__((ext_vector_type(4))) float f32x4;

__device__ __forceinline__ short f2bf(float f) {
  union { float f; unsigned u; } v; v.f = f;
  unsigned r = v.u + 0x7fffu + ((v.u >> 16) & 1u);
  return (short)(r >> 16);
}

__device__ __forceinline__ float bf2f(short s) {
  union { unsigned u; float f; } v;
  v.u = ((unsigned)(unsigned short)s) << 16;
  return v.f;
}

__device__ __forceinline__ short8 load_a8(const float* p) {
  const f32x4* q = (const f32x4*)p;
  f32x4 x0 = q[0], x1 = q[1];
  short8 r;
  r[0]=f2bf(x0[0]); r[1]=f2bf(x0[1]); r[2]=f2bf(x0[2]); r[3]=f2bf(x0[3]);
  r[4]=f2bf(x1[0]); r[5]=f2bf(x1[1]); r[6]=f2bf(x1[2]); r[7]=f2bf(x1[3]);
  return r;
}

// swizzled LDS index (in shorts). rowBytes = row stride in bytes.
__device__ __forceinline__ int swz(int row, int col, int rowBytes) {
  int b = row * rowBytes + col * 2;
  b ^= (row & 7) << 4;
  return b >> 1;
}

// Cast h, g to bf16 + degree count + weight pack, all fused (one launch).
__global__ void cast_kernel(const float* __restrict__ h, const float* __restrict__ g,
                            const int* __restrict__ ei,
                            const float* __restrict__ Wm1, const float* __restrict__ Wm2,
                            const float* __restrict__ We1, const float* __restrict__ We2,
                            const float* __restrict__ Wh1, const float* __restrict__ Wh2,
                            short* __restrict__ h_bf, short* __restrict__ g_bf,
                            int* __restrict__ deg, short* __restrict__ pout) {
  int gid = blockIdx.x * 256 + threadIdx.x;
  const int H4 = NN * HD / 4;          // 1,600,000
  const int G4 = NG * GD / 4;          // 8,192
  if (gid < H4) {
    f32x4 v = ((const f32x4*)h)[gid];
    short4v r; r[0]=f2bf(v[0]); r[1]=f2bf(v[1]); r[2]=f2bf(v[2]); r[3]=f2bf(v[3]);
    *(short4v*)(h_bf + gid * 4) = r;
  } else if (gid < H4 + G4) {
    int i = gid - H4;
    f32x4 v = ((const f32x4*)g)[i];
    short4v r; r[0]=f2bf(v[0]); r[1]=f2bf(v[1]); r[2]=f2bf(v[2]); r[3]=f2bf(v[3]);
    *(short4v*)(g_bf + i * 4) = r;
  } else if (gid < H4 + G4 + NE) {
    int i = gid - H4 - G4;
    atomicAdd(&deg[ei[NE + i]], 1);
  } else if (gid < H4 + G4 + NE + 135168) {
    int pid = gid - H4 - G4 - NE;
    const float* W; int Ncol, base, idx;
    if (pid < 49152)       { W = Wm1; Ncol = 128; base = 0;      idx = pid; }
    else if (pid < 65536)  { W = Wm2; Ncol = 128; base = 49152;  idx = pid - 49152; }
    else if (pid < 73728)  { W = We1; Ncol = 64;  base = 65536;  idx = pid - 65536; }
    else if (pid < 77824)  { W = We2; Ncol = 64;  base = 73728;  idx = pid - 73728; }
    else if (pid < 118784) { W = Wh1; Ncol = 128; base = 77824;  idx = pid - 77824; }
    else                   { W = Wh2; Ncol = 128; base = 118784; idx = pid - 118784; }
    int k = idx / Ncol, n = idx % Ncol;
    pout[base + (k >> 3) * Ncol * 8 + n * 8 + (k & 7)] = f2bf(W[idx]);
  }
}

__global__ __launch_bounds__(1024) void scan_kernel(int* __restrict__ deg) {
  __shared__ int psum[1024];
  const int CH = 49;
  int t = threadIdx.x;
  int lo = t * CH, hi = lo + CH; if (hi > NN) hi = NN; if (lo > NN) lo = NN;
  int s = 0;
  for (int i = lo; i < hi; ++i) s += deg[i];
  psum[t] = s;
  __syncthreads();
  for (int d = 1; d < 1024; d <<= 1) {
    int v = (t >= d) ? psum[t - d] : 0;
    __syncthreads();
    psum[t] += v;
    __syncthreads();
  }
  int run = (t == 0) ? 0 : psum[t - 1];
  for (int i = lo; i < hi; ++i) { int v = deg[i]; deg[i] = run; run += v; }
}

__global__ void scatter_kernel(const int* __restrict__ ei, int* __restrict__ off,
                               int* __restrict__ elist) {
  int i = blockIdx.x * 256 + threadIdx.x;
  if (i < NE) {
    int d = ei[NE + i];
    int p = atomicAdd(&off[d], 1);
    elist[p] = i;
  }
}

// stage one 8KB chunk (4096 shorts): 256 threads x 2 x 16B, coalesced.
#define STAGE(Wp, c, b) do {                                                  \
    const short* _s = (Wp) + (size_t)(c) * 4096;                              \
    short8 _v0 = *(const short8*)(_s + tid * 8);                              \
    short8 _v1 = *(const short8*)(_s + 2048 + tid * 8);                       \
    *(short8*)&bufB[(b)][tid * 8] = _v0;                                      \
    *(short8*)&bufB[(b)][2048 + tid * 8] = _v1;                               \
  } while (0)

// Edge kernel v11 (R12 config — best measured): 16x16x32, 4 waves x 16 edges,
// 64/block, Wm1/Wm2 LDS dbuf staging, XCD swizzle, e f32 hoisted, no setprio.
__global__ __launch_bounds__(256) void edge_kernel(
    const short* __restrict__ h_bf, const int* __restrict__ ei,
    const float* __restrict__ e, const short* __restrict__ g_bf,
    const int* __restrict__ batch, const int* __restrict__ elist,
    const short* __restrict__ pWm1, const float* __restrict__ bm1,
    const short* __restrict__ pWm2, const float* __restrict__ bm2,
    const float* __restrict__ Wma, const float* __restrict__ bma,
    const short* __restrict__ pWe1, const float* __restrict__ be1,
    const short* __restrict__ pWe2, const float* __restrict__ be2,
    float* __restrict__ e_out, float* __restrict__ m_aggr) {
  __shared__ short lds_m[EB * 128];   // 16 KB
  __shared__ short bufB[2][4096];     // 16 KB
  __shared__ float att_s[EB];
  __shared__ int sdst[EB];
  __shared__ int seid[EB];
  short* ebuf = lds_m;

  const int tid = threadIdx.x;
  const int w = tid >> 6;
  const int lane = tid & 63;
  const int row16 = lane & 15;
  const int quad = lane >> 4;

  // bijective XCD-chunked swizzle (m204)
  int nwg = gridDim.x;
  int q = nwg >> 3, rr = nwg & 7;
  int xcd = blockIdx.x & 7;
  int idx = blockIdx.x >> 3;
  int bid = (xcd < rr ? xcd * (q + 1) : rr * (q + 1) + (xcd - rr) * q) + idx;
  const int eb = bid * EB;

  if (tid < EB) {
    int eid = elist[eb + tid];
    seid[tid] = eid;
    sdst[tid] = ei[NE + eid];
  }

  const int eidr = elist[eb + w * 16 + row16];
  const int dstr = ei[NE + eidr];
  const int srcr = ei[eidr];
  const int gbr = batch[dstr];

  const short* seg0 = h_bf + (size_t)srcr * HD;
  const short* seg1 = h_bf + (size_t)dstr * HD;
  const short* seg3 = g_bf + (size_t)gbr * GD;

  // hoist e row once: f32 -> bf16 regs
  short8 ea0, ea1;
  {
    const float* ep = e + (size_t)eidr * ED + quad * 8;
    ea0 = load_a8(ep);
    ea1 = load_a8(ep + 32);
  }

  // ---- layer m1: [16,384] @ [384,128]; 12 staged k-chunks
  f32x4 acc[8];
#pragma unroll
  for (int t = 0; t < 8; ++t) acc[t] = (f32x4)0.0f;

  STAGE(pWm1, 0, 0);
  __syncthreads();
#pragma unroll
  for (int c = 0; c < 12; ++c) {
    if (c < 11) STAGE(pWm1, c + 1, (c + 1) & 1);
    else        STAGE(pWm2, 0, 0);
    short8 a;
    if (c < 4)       a = *(const short8*)(seg0 + c * 32 + quad * 8);
    else if (c < 8)  a = *(const short8*)(seg1 + (c - 4) * 32 + quad * 8);
    else if (c == 8) a = ea0;
    else if (c == 9) a = ea1;
    else             a = *(const short8*)(seg3 + (c - 10) * 32 + quad * 8);
    const short* bc = &bufB[c & 1][quad * 1024 + row16 * 8];
#pragma unroll
    for (int t = 0; t < 8; ++t) {
      short8 b = *(const short8*)(bc + t * 128);
      acc[t] = __builtin_amdgcn_mfma_f32_16x16x32_bf16(a, b, acc[t], 0, 0, 0);
    }
    __syncthreads();
  }
#pragma unroll
  for (int t = 0; t < 8; ++t) {
    float b1 = bm1[t * 16 + row16];
#pragma unroll
    for (int r = 0; r < 4; ++r) {
      float y = fmaxf(acc[t][r] + b1, 0.f);
      lds_m[swz(w * 16 + quad * 4 + r, t * 16 + row16, 256)] = f2bf(y);
    }
  }

  // ---- layer m2: [16,128] @ [128,128]; 4 staged k-chunks
  f32x4 acc2[8];
#pragma unroll
  for (int t = 0; t < 8; ++t) acc2[t] = (f32x4)0.0f;
#pragma unroll
  for (int c = 0; c < 4; ++c) {
    if (c < 3) STAGE(pWm2, c + 1, (c + 1) & 1);
    short8 a = *(const short8*)&lds_m[swz(w * 16 + row16, c * 32 + quad * 8, 256)];
    const short* bc = &bufB[c & 1][quad * 1024 + row16 * 8];
#pragma unroll
    for (int t = 0; t < 8; ++t) {
      short8 b = *(const short8*)(bc + t * 128);
      acc2[t] = __builtin_amdgcn_mfma_f32_16x16x32_bf16(a, b, acc2[t], 0, 0, 0);
    }
    __syncthreads();
  }

  // m = relu(acc2+b) -> lds_m (raw m; att applied at flush); att partials
  float p[4] = {0.f, 0.f, 0.f, 0.f};
#pragma unroll
  for (int t = 0; t < 8; ++t) {
    float b2 = bm2[t * 16 + row16];
    float wv = Wma[t * 16 + row16];
#pragma unroll
    for (int r = 0; r < 4; ++r) {
      float y = fmaxf(acc2[t][r] + b2, 0.f);
      lds_m[swz(w * 16 + quad * 4 + r, t * 16 + row16, 256)] = f2bf(y);
      p[r] += y * wv;
    }
  }

#pragma unroll
  for (int s = 1; s < 16; s <<= 1) {
#pragma unroll
    for (int r = 0; r < 4; ++r) p[r] += __shfl_xor(p[r], s, 64);
  }
  {
    float bma0 = bma[0];
    if (row16 == 0) {
#pragma unroll
      for (int r = 0; r < 4; ++r)
        att_s[w * 16 + quad * 4 + r] = 1.f / (1.f + __expf(-(p[r] + bma0)));
    }
  }

  // ---- layer e1: [16,128] @ [128,64] (A = m from lds_m, B from L2)
  f32x4 acc3[4];
#pragma unroll
  for (int t = 0; t < 4; ++t) acc3[t] = (f32x4)0.0f;
#pragma unroll
  for (int c = 0; c < 4; ++c) {
    short8 a = *(const short8*)&lds_m[swz(w * 16 + row16, c * 32 + quad * 8, 256)];
    const short* bp = pWe1 + (size_t)(c * 4 + quad) * (ED * 8) + row16 * 8;
#pragma unroll
    for (int t = 0; t < 4; ++t) {
      short8 b = *(const short8*)(bp + t * 16 * 8);
      acc3[t] = __builtin_amdgcn_mfma_f32_16x16x32_bf16(a, b, acc3[t], 0, 0, 0);
    }
  }

  __syncthreads();

  // ---- segmented flush: 64 col-pairs x 4 row-quarters of 16 (quarter == wave)
  {
    int cp = tid & 63;
    int r0 = (tid >> 6) * 16;
    int cur = sdst[r0];
    float s0 = 0.f, s1 = 0.f;
    bool first = true;
#pragma unroll 1
    for (int r = r0; r < r0 + 16; ++r) {
      int d = sdst[r];
      unsigned u = *(const unsigned*)&lds_m[swz(r, cp * 2, 256)];
      float av = att_s[r];
      float v0 = bf2f((short)(u & 0xffffu)) * av;
      float v1 = bf2f((short)(u >> 16)) * av;
      if (d != cur) {
        if (first) {
          atomicAdd(&m_aggr[(size_t)cur * HID + cp * 2], s0);
          atomicAdd(&m_aggr[(size_t)cur * HID + cp * 2 + 1], s1);
        } else {
          f32x2 st; st[0] = s0; st[1] = s1;
          *(f32x2*)&m_aggr[(size_t)cur * HID + cp * 2] = st;
        }
        first = false; cur = d; s0 = v0; s1 = v1;
      } else {
        s0 += v0; s1 += v1;
      }
    }
    atomicAdd(&m_aggr[(size_t)cur * HID + cp * 2], s0);
    atomicAdd(&m_aggr[(size_t)cur * HID + cp * 2 + 1], s1);
  }

  __syncthreads();

  // ---- e1 bias+relu -> ebuf (overlays lds_m; no m reads after barrier2)
#pragma unroll
  for (int t = 0; t < 4; ++t) {
    float b1 = be1[t * 16 + row16];
#pragma unroll
    for (int r = 0; r < 4; ++r) {
      float y = fmaxf(acc3[t][r] + b1, 0.f);
      ebuf[swz(w * 16 + quad * 4 + r, t * 16 + row16, 128)] = f2bf(y);
    }
  }

  // ---- layer e2: [16,64] @ [64,64]; 2 k-chunks (B from L2)
  f32x4 acc4[4];
#pragma unroll
  for (int t = 0; t < 4; ++t) acc4[t] = (f32x4)0.0f;
#pragma unroll
  for (int c = 0; c < 2; ++c) {
    short8 a = *(const short8*)&ebuf[swz(w * 16 + row16, c * 32 + quad * 8, 128)];
    const short* bp = pWe2 + (size_t)(c * 4 + quad) * (ED * 8) + row16 * 8;
#pragma unroll
    for (int t = 0; t < 4; ++t) {
      short8 b = *(const short8*)(bp + t * 16 * 8);
      acc4[t] = __builtin_amdgcn_mfma_f32_16x16x32_bf16(a, b, acc4[t], 0, 0, 0);
    }
  }

  // ---- e_out = relu(e + upd); residual from e f32 (L2-hot: read in m1)
  int eidS[4];
#pragma unroll
  for (int r = 0; r < 4; ++r) eidS[r] = seid[w * 16 + quad * 4 + r];
#pragma unroll
  for (int t = 0; t < 4; ++t) {
    float b2 = be2[t * 16 + row16];
#pragma unroll
    for (int r = 0; r < 4; ++r) {
      int col = t * 16 + row16;
      float res = e[(size_t)eidS[r] * ED + col];
      float v = res + acc4[t][r] + b2;
      e_out[(size_t)eidS[r] * ED + col] = fmaxf(v, 0.f);
    }
  }
}
#undef STAGE

// Node kernel (R12 unstaged config, best total): batch sorted -> segmented
// flush for h_aggr. R15 delta: residual read from h_bf (-25.6MB HBM).
__global__ __launch_bounds__(256) void node_kernel(
    const short* __restrict__ h_bf,
    const float* __restrict__ m_aggr, const short* __restrict__ g_bf,
    const int* __restrict__ batch,
    const short* __restrict__ pWh1, const float* __restrict__ bh1,
    const short* __restrict__ pWh2, const float* __restrict__ bh2,
    const float* __restrict__ Wha, const float* __restrict__ bha,
    float* __restrict__ h_out, float* __restrict__ h_aggr) {
  __shared__ short lds_y[4][16 * 128];
  __shared__ int sbat[64];

  const int wave = threadIdx.x >> 6;
  const int lane = threadIdx.x & 63;
  const int row16 = lane & 15;
  const int quad = lane >> 4;
  const int nbase = blockIdx.x * 64 + wave * 16;

  int nA = nbase + row16;
  int nAc = nA < NN ? nA : NN - 1;
  int gbA = batch[nAc];
  if (quad == 0) sbat[wave * 16 + row16] = (nA < NN) ? gbA : -1;

  short8 afr[10];
  {
    const short* s0 = h_bf + (size_t)nAc * HD;
    const float* s1 = m_aggr + (size_t)nAc * HID;
    const short* s2 = g_bf + (size_t)gbA * GD;
#pragma unroll
    for (int c = 0; c < 4; ++c) afr[c] = *(const short8*)(s0 + c * 32 + quad * 8);
#pragma unroll
    for (int c = 0; c < 4; ++c) afr[4 + c] = load_a8(s1 + c * 32 + quad * 8);
    afr[8] = *(const short8*)(s2 + quad * 8);
    afr[9] = *(const short8*)(s2 + 32 + quad * 8);
  }

  f32x4 acc[8];
#pragma unroll
  for (int t = 0; t < 8; ++t) acc[t] = (f32x4)0.0f;
#pragma unroll
  for (int c = 0; c < 10; ++c) {
    const short* bp = pWh1 + (size_t)(c * 4 + quad) * HD * 8 + row16 * 8;
#pragma unroll
    for (int t = 0; t < 8; ++t) {
      short8 b = *(const short8*)(bp + t * 16 * 8);
      acc[t] = __builtin_amdgcn_mfma_f32_16x16x32_bf16(afr[c], b, acc[t], 0, 0, 0);
    }
  }
#pragma unroll
  for (int t = 0; t < 8; ++t) {
    float b1 = bh1[t * 16 + row16];
#pragma unroll
    for (int r = 0; r < 4; ++r) {
      float y = fmaxf(acc[t][r] + b1, 0.f);
      lds_y[wave][swz(quad * 4 + r, t * 16 + row16, 256)] = f2bf(y);
    }
  }

  f32x4 acc2[8];
#pragma unroll
  for (int t = 0; t < 8; ++t) acc2[t] = (f32x4)0.0f;
#pragma unroll
  for (int c = 0; c < 4; ++c) {
    short8 a = *(const short8*)&lds_y[wave][swz(row16, c * 32 + quad * 8, 256)];
    const short* bp = pWh2 + (size_t)(c * 4 + quad) * HD * 8 + row16 * 8;
#pragma unroll
    for (int t = 0; t < 8; ++t) {
      short8 b = *(const short8*)(bp + t * 16 * 8);
      acc2[t] = __builtin_amdgcn_mfma_f32_16x16x32_bf16(a, b, acc2[t], 0, 0, 0);
    }
  }

  float hval[8][4];
  int nS[4];
#pragma unroll
  for (int r = 0; r < 4; ++r) nS[r] = nbase + quad * 4 + r;
#pragma unroll
  for (int t = 0; t < 8; ++t) {
    float b2 = bh2[t * 16 + row16];
#pragma unroll
    for (int r = 0; r < 4; ++r) {
      float v = 0.f;
      if (nS[r] < NN) {
        float res = bf2f(h_bf[(size_t)nS[r] * HD + t * 16 + row16]);
        v = res + acc2[t][r] + b2;
        v = fmaxf(v, 0.f);
        h_out[(size_t)nS[r] * HD + t * 16 + row16] = v;
      }
      hval[t][r] = v;
    }
  }

  // h_att (linear)
  float part[4] = {0.f, 0.f, 0.f, 0.f};
#pragma unroll
  for (int t = 0; t < 8; ++t) {
    float w = Wha[t * 16 + row16];
#pragma unroll
    for (int r = 0; r < 4; ++r) part[r] += hval[t][r] * w;
  }
#pragma unroll
  for (int s = 1; s < 16; s <<= 1) {
#pragma unroll
    for (int r = 0; r < 4; ++r) part[r] += __shfl_xor(part[r], s, 64);
  }
  float bha0 = bha[0];
#pragma unroll
  for (int t = 0; t < 8; ++t)
#pragma unroll
    for (int r = 0; r < 4; ++r)
      lds_y[wave][swz(quad * 4 + r, t * 16 + row16, 256)] =
          f2bf((part[r] + bha0) * hval[t][r]);

  __syncthreads();

  {
    int col = threadIdx.x & 127;
    int r0 = (threadIdx.x >> 7) * 32;
    int cur = sbat[r0];
    float sum = 0.f;
    bool first = true;
#pragma unroll 1
    for (int r = r0; r < r0 + 32; ++r) {
      int d = sbat[r];
      float v = bf2f(lds_y[r >> 4][swz(r & 15, col, 256)]);
      if (d != cur) {
        if (cur >= 0) {
          if (first) atomicAdd(&h_aggr[(size_t)cur * HD + col], sum);
          else h_aggr[(size_t)cur * HD + col] = sum;
        }
        first = false; cur = d; sum = v;
      } else {
        sum += v;
      }
    }
    if (cur >= 0) atomicAdd(&h_aggr[(size_t)cur * HD + col], sum);
  }
}

// Global kernel: one wave per graph row
__global__ void g_kernel(const float* __restrict__ g, const float* __restrict__ h_aggr,
                         const float* __restrict__ Wg1, const float* __restrict__ bg1,
                         const float* __restrict__ Wg2, const float* __restrict__ bg2,
                         float* __restrict__ g_out) {
  __shared__ float cat[192];
  __shared__ float y1[64];
  int r = blockIdx.x;
  int t = threadIdx.x;  // 64 threads
  cat[t] = g[(size_t)r * GD + t];
  cat[64 + t] = h_aggr[(size_t)r * HD + t];
  cat[128 + t] = h_aggr[(size_t)r * HD + 64 + t];
  __syncthreads();
  float a = bg1[t];
  for (int k = 0; k < 192; ++k) a += cat[k] * Wg1[k * 64 + t];
  y1[t] = fmaxf(a, 0.f);
  __syncthreads();
  float b = bg2[t];
  for (int k = 0; k < 64; ++k) b += y1[k] * Wg2[k * 64 + t];
  float v = g[(size_t)r * GD + t] + b;
  g_out[(size_t)r * GD + t] = fmaxf(v, 0.f);
}

extern "C" void kernel_launch(void* const* d_in, const int* in_sizes, int n_in,
                              void* d_out, int out_size, void* d_ws, size_t ws_size,
                              hipStream_t stream) {
  const float* h = (const float*)d_in[0];
  const int* ei = (const int*)d_in[1];
  const float* e = (const float*)d_in[2];
  const float* g = (const float*)d_in[3];
  const int* batch = (const int*)d_in[4];
  const float* Wm1 = (const float*)d_in[5];
  const float* bm1 = (const float*)d_in[6];
  const float* Wm2 = (const float*)d_in[7];
  const float* bm2 = (const float*)d_in[8];
  const float* Wma = (const float*)d_in[9];
  const float* bma = (const float*)d_in[10];
  const float* We1 = (const float*)d_in[11];
  const float* be1 = (const float*)d_in[12];
  const float* We2 = (const float*)d_in[13];
  const float* be2 = (const float*)d_in[14];
  const float* Wh1 = (const float*)d_in[15];
  const float* bh1 = (const float*)d_in[16];
  const float* Wh2 = (const float*)d_in[17];
  const float* bh2 = (const float*)d_in[18];
  const float* Wha = (const float*)d_in[19];
  const float* bha = (const float*)d_in[20];
  const float* Wg1 = (const float*)d_in[21];
  const float* bg1 = (const float*)d_in[22];
  const float* Wg2 = (const float*)d_in[23];
  const float* bg2 = (const float*)d_in[24];

  float* out = (float*)d_out;
  float* h_out = out;
  float* e_out = out + (size_t)NN * HD;
  float* g_out = e_out + (size_t)NE * ED;

  char* ws = (char*)d_ws;
  float* m_aggr = (float*)ws;                     // 25,600,000 B
  float* h_aggr = (float*)(ws + 25600000);        // 262,144 B
  short* packed = (short*)(ws + 25862144);        // 270,336 B
  int* deg      = (int*)(ws + 26132480);          // 200,000 B
  int* elist    = (int*)(ws + 26332480);          // 3,200,000 B
  short* h_bf   = (short*)(ws + 29532480);        // 12,800,000 B
  short* g_bf   = (short*)(ws + 42332480);        // 65,536 B
  short* pWm1 = packed;
  short* pWm2 = packed + 49152;
  short* pWe1 = packed + 65536;
  short* pWe2 = packed + 73728;
  short* pWh1 = packed + 77824;
  short* pWh2 = packed + 118784;

  hipMemsetAsync(m_aggr, 0, (size_t)NN * HID * 4, stream);
  hipMemsetAsync(h_aggr, 0, (size_t)NG * HD * 4, stream);
  hipMemsetAsync(deg, 0, (size_t)NN * 4, stream);

  // grid: H4 + G4 + NE + pack(135168) = 2,543,360 threads
  cast_kernel<<<(2543360 + 255) / 256, 256, 0, stream>>>(
      h, g, ei, Wm1, Wm2, We1, We2, Wh1, Wh2, h_bf, g_bf, deg, packed);
  scan_kernel<<<1, 1024, 0, stream>>>(deg);
  scatter_kernel<<<(NE + 255) / 256, 256, 0, stream>>>(ei, deg, elist);

  edge_kernel<<<NE / EB, 256, 0, stream>>>(h_bf, ei, e, g_bf, batch, elist,
                                           pWm1, bm1, pWm2, bm2, Wma, bma,
                                           pWe1, be1, pWe2, be2, e_out, m_aggr);

  node_kernel<<<(NN + 63) / 64, 256, 0, stream>>>(h_bf, m_aggr, g_bf, batch,
                                                  pWh1, bh1, pWh2, bh2, Wha, bha,
                                                  h_out, h_aggr);

  g_kernel<<<NG, 64, 0, stream>>>(g, h_aggr, Wg1, bg1, Wg2, bg2, g_out);
}